// Round 7
// baseline (45.201 us; speedup 1.0000x reference)
//
#include <hip/hip_runtime.h>
#include <math.h>

#define DIM 512
#define NNBR 8
#define NCTX 16
#define BATCH 1024

typedef __attribute__((ext_vector_type(8))) short bf16x8;
typedef __attribute__((ext_vector_type(4))) float f32x4;

// RNE float -> bf16 bits
static __device__ __forceinline__ ushort f2bf(float f) {
    uint u = __float_as_uint(f);
    return (ushort)((u + 0x7fffu + ((u >> 16) & 1u)) >> 16);
}

// ---------------- K1: hidden_bf (one block/row, proven form) + W_agg->bf16 + zero accs ----------------
__global__ __launch_bounds__(512) void k_hidden(
    const int* __restrict__ u, const int* __restrict__ v,
    const int* __restrict__ adj_ent, const int* __restrict__ adj_rel,
    const float* __restrict__ usr_emb, const float* __restrict__ ent_emb,
    const float* __restrict__ rel_emb, const float* __restrict__ W_agg,
    ushort* __restrict__ hidden_bf, ushort* __restrict__ Wb,
    float* __restrict__ out_acc, float* __restrict__ c_acc, int* __restrict__ done)
{
    const int b = blockIdx.x;
    const int t = threadIdx.x;           // d index
    if (b < 512) {                        // W_agg -> bf16 (512*512 elems)
        const size_t wi = (size_t)b * 512 + t;
        Wb[wi] = f2bf(W_agg[wi]);
    }
    // zero accumulators + ticket (kernel-boundary release makes these visible to K2)
    if (b == 0) {
        out_acc[t] = 0.0f;
        out_acc[512 + t] = 0.0f;
        if (t == 0) *done = 0;
    }
    if (b >= 1 && b <= 16) c_acc[(size_t)(b - 1) * 512 + t] = 0.0f;

    __shared__ int s_ne[NNBR], s_nr[NNBR];
    __shared__ float s_sc[NNBR];
    const int vid = v[b];
    const int uid = u[b];
    if (t < NNBR) {
        s_ne[t] = adj_ent[vid * NNBR + t];
        s_nr[t] = adj_rel[vid * NNBR + t];
        s_sc[t] = 0.0f;
    }
    __syncthreads();

    const float user_d = usr_emb[(size_t)uid * DIM + t];
    const float self_d = ent_emb[(size_t)vid * DIM + t];
    float nbr[NNBR], p[NNBR];
#pragma unroll
    for (int k = 0; k < NNBR; ++k) {
        nbr[k] = ent_emb[(size_t)s_ne[k] * DIM + t];
        p[k] = user_d * rel_emb[(size_t)s_nr[k] * DIM + t];
    }
#pragma unroll
    for (int k = 0; k < NNBR; ++k) {
#pragma unroll
        for (int off = 32; off >= 1; off >>= 1)
            p[k] += __shfl_xor(p[k], off, 64);
    }
    if ((t & 63) == 0) {
#pragma unroll
        for (int k = 0; k < NNBR; ++k) atomicAdd(&s_sc[k], p[k]);
    }
    __syncthreads();

    float m = s_sc[0];
#pragma unroll
    for (int k = 1; k < NNBR; ++k) m = fmaxf(m, s_sc[k]);
    float e[NNBR], ssum = 0.0f;
#pragma unroll
    for (int k = 0; k < NNBR; ++k) { e[k] = expf(s_sc[k] - m); ssum += e[k]; }
    const float inv = 1.0f / ssum;
    float agg = 0.0f;
#pragma unroll
    for (int k = 0; k < NNBR; ++k) agg = fmaf(e[k], nbr[k], agg);

    hidden_bf[(size_t)b * DIM + t] = f2bf(self_d + agg * inv);
}

// ---------------- K2: fused bf16-MFMA GEMM + tanh + atomic out/c partials + last-block finish ----------------
// grid (16,8) x 256 thr = 4 waves (2x2 of 32x32), block tile 64x64.
__global__ __launch_bounds__(256) void k_item_fused(
    const ushort* __restrict__ hidden, const ushort* __restrict__ Wb,
    const float* __restrict__ b_agg, const int* __restrict__ u,
    const float* __restrict__ usr_emb, const float* __restrict__ W_lin,
    const float* __restrict__ b_lin,
    float* __restrict__ out_acc, float* __restrict__ c_acc,
    int* __restrict__ done,
    float* __restrict__ out, float* __restrict__ c)
{
    __shared__ float c_blk[2][NCTX][64];
    const int tid = threadIdx.x;
    const int lane = tid & 63, w = tid >> 6;
    const int wr = w >> 1, wc = w & 1;
    const int m0 = blockIdx.x * 64 + wr * 32;
    const int n0 = blockIdx.y * 64 + wc * 32;
    const int r = lane & 15;             // A-row / B-col within frag
    const int kb = lane >> 4;            // k-block (8 elems each)

    f32x4 acc[2][2] = {};
    const ushort* Ap = hidden + (size_t)(m0 + r) * DIM + kb * 8;
    const ushort* Bp = Wb     + (size_t)(n0 + r) * DIM + kb * 8;

#pragma unroll
    for (int k0 = 0; k0 < DIM; k0 += 32) {
        bf16x8 a0 = *(const bf16x8*)(Ap + k0);
        bf16x8 a1 = *(const bf16x8*)(Ap + 16 * DIM + k0);
        bf16x8 b0 = *(const bf16x8*)(Bp + k0);
        bf16x8 b1 = *(const bf16x8*)(Bp + 16 * DIM + k0);
        acc[0][0] = __builtin_amdgcn_mfma_f32_16x16x32_bf16(a0, b0, acc[0][0], 0, 0, 0);
        acc[0][1] = __builtin_amdgcn_mfma_f32_16x16x32_bf16(a0, b1, acc[0][1], 0, 0, 0);
        acc[1][0] = __builtin_amdgcn_mfma_f32_16x16x32_bf16(a1, b0, acc[1][0], 0, 0, 0);
        acc[1][1] = __builtin_amdgcn_mfma_f32_16x16x32_bf16(a1, b1, acc[1][1], 0, 0, 0);
    }

    // C/D layout: col = lane&15 (+16*ni), row = mi*16 + kb*4 + reg
    float cacc[NCTX][2] = {};
#pragma unroll
    for (int mi = 0; mi < 2; ++mi)
#pragma unroll
        for (int j = 0; j < 4; ++j) {
            const int row = m0 + mi * 16 + kb * 4 + j;
            const int uid = u[row];
            float vals[2];
            float dp = 0.0f;
#pragma unroll
            for (int ni = 0; ni < 2; ++ni) {
                const int col = n0 + ni * 16 + r;
                const float vv = tanhf(acc[mi][ni][j] + b_agg[col]);
                vals[ni] = vv;
                dp = fmaf(vv, usr_emb[(size_t)uid * DIM + col], dp);
            }
#pragma unroll
            for (int n = 0; n < NCTX; ++n) {
                const float wl = W_lin[n * BATCH + row];   // uniform across 16-lane group
                cacc[n][0] = fmaf(wl, vals[0], cacc[n][0]);
                cacc[n][1] = fmaf(wl, vals[1], cacc[n][1]);
            }
            dp += __shfl_xor(dp, 1, 64);
            dp += __shfl_xor(dp, 2, 64);
            dp += __shfl_xor(dp, 4, 64);
            dp += __shfl_xor(dp, 8, 64);
            if (r == 0) atomicAdd(&out_acc[row], dp);
        }

#pragma unroll
    for (int n = 0; n < NCTX; ++n)
#pragma unroll
        for (int ni = 0; ni < 2; ++ni) {
            float vv = cacc[n][ni];
            vv += __shfl_xor(vv, 16, 64);
            vv += __shfl_xor(vv, 32, 64);
            if (kb == 0) c_blk[wr][n][wc * 32 + ni * 16 + r] = vv;
        }
    __syncthreads();

    const int base = tid * 4;
#pragma unroll
    for (int e2 = 0; e2 < 4; ++e2) {
        const int idx = base + e2;           // n*64 + col
        const int n = idx >> 6, col = idx & 63;
        atomicAdd(&c_acc[(size_t)n * DIM + blockIdx.y * 64 + col],
                  c_blk[0][n][col] + c_blk[1][n][col]);
    }

    // ---- last-block ticket (NO threadfence: atomics are already device-coherent;
    //      we only need our own atomics acknowledged before the ticket) ----
    __shared__ int s_last;
    asm volatile("s_waitcnt vmcnt(0)" ::: "memory");
    __syncthreads();
    if (tid == 0) s_last = atomicAdd(done, 1);
    __syncthreads();
    if (s_last == 127) {
        // all 128 blocks' data atomics completed at the coherent point; read
        // them back with atomic RMW (+0.0f) to bypass any stale local cache.
        for (int i = tid; i < BATCH; i += 256) {
            const float x = atomicAdd(&out_acc[i], 0.0f);
            out[i] = 1.0f / (1.0f + expf(-x));
        }
        for (int i = tid; i < NCTX * DIM; i += 256) {
            const float x = atomicAdd(&c_acc[i], 0.0f);
            c[i] = x + b_lin[i >> 9];
        }
    }
}

extern "C" void kernel_launch(void* const* d_in, const int* in_sizes, int n_in,
                              void* d_out, int out_size, void* d_ws, size_t ws_size,
                              hipStream_t stream) {
    const int*   u       = (const int*)  d_in[0];
    const int*   v       = (const int*)  d_in[1];
    const int*   adj_ent = (const int*)  d_in[2];
    const int*   adj_rel = (const int*)  d_in[3];
    const float* usr_emb = (const float*)d_in[4];
    const float* ent_emb = (const float*)d_in[5];
    const float* rel_emb = (const float*)d_in[6];
    const float* W_agg   = (const float*)d_in[7];
    const float* b_agg   = (const float*)d_in[8];
    const float* W_lin   = (const float*)d_in[9];
    const float* b_lin   = (const float*)d_in[10];

    float* out = (float*)d_out;            // [1024]
    float* c   = out + BATCH;              // [16][512]

    // ws layout: hidden (1MB) | Wb (0.5MB) | out_acc (4KB) | c_acc (32KB) | done (4B)
    ushort* hidden  = (ushort*)d_ws;
    ushort* Wb      = hidden + (size_t)BATCH * DIM;
    float*  out_acc = (float*)(Wb + (size_t)DIM * DIM);
    float*  c_acc   = out_acc + BATCH;
    int*    done    = (int*)(c_acc + (size_t)NCTX * DIM);

    k_hidden<<<BATCH, 512, 0, stream>>>(u, v, adj_ent, adj_rel,
                                        usr_emb, ent_emb, rel_emb, W_agg,
                                        hidden, Wb, out_acc, c_acc, done);
    k_item_fused<<<dim3(BATCH / 64, DIM / 64), 256, 0, stream>>>(
        hidden, Wb, b_agg, u, usr_emb, W_lin, b_lin, out_acc, c_acc, done, out, c);
}

// Round 8
// 43.020 us; speedup vs baseline: 1.0507x; 1.0507x over previous
//
#include <hip/hip_runtime.h>
#include <math.h>

#define DIM 512
#define NNBR 8
#define NCTX 16
#define BATCH 1024

typedef __attribute__((ext_vector_type(8))) short bf16x8;
typedef __attribute__((ext_vector_type(4))) float f32x4;

// RNE float -> bf16 bits
static __device__ __forceinline__ ushort f2bf(float f) {
    uint u = __float_as_uint(f);
    return (ushort)((u + 0x7fffu + ((u >> 16) & 1u)) >> 16);
}

// ---------------- K1: hidden_bf (one block/row, proven R6 form) + W_agg->bf16 + c=b_lin init ----------------
__global__ __launch_bounds__(512) void k_hidden(
    const int* __restrict__ u, const int* __restrict__ v,
    const int* __restrict__ adj_ent, const int* __restrict__ adj_rel,
    const float* __restrict__ usr_emb, const float* __restrict__ ent_emb,
    const float* __restrict__ rel_emb, const float* __restrict__ W_agg,
    const float* __restrict__ b_lin,
    ushort* __restrict__ hidden_bf, ushort* __restrict__ Wb,
    float* __restrict__ c)
{
    const int b = blockIdx.x;
    const int t = threadIdx.x;           // d index
    if (b < 512) {                        // W_agg -> bf16 (512*512 elems)
        const size_t wi = (size_t)b * 512 + t;
        Wb[wi] = f2bf(W_agg[wi]);
    }
    // c starts at bias; K2 atomically accumulates k-slice partials on top.
    if (b < NCTX) c[(size_t)b * DIM + t] = b_lin[b];

    __shared__ int s_ne[NNBR], s_nr[NNBR];
    __shared__ float s_sc[NNBR];
    const int vid = v[b];
    const int uid = u[b];
    if (t < NNBR) {
        s_ne[t] = adj_ent[vid * NNBR + t];
        s_nr[t] = adj_rel[vid * NNBR + t];
        s_sc[t] = 0.0f;
    }
    __syncthreads();

    const float user_d = usr_emb[(size_t)uid * DIM + t];
    const float self_d = ent_emb[(size_t)vid * DIM + t];
    float nbr[NNBR], p[NNBR];
#pragma unroll
    for (int k = 0; k < NNBR; ++k) {
        nbr[k] = ent_emb[(size_t)s_ne[k] * DIM + t];
        p[k] = user_d * rel_emb[(size_t)s_nr[k] * DIM + t];
    }
#pragma unroll
    for (int k = 0; k < NNBR; ++k) {
#pragma unroll
        for (int off = 32; off >= 1; off >>= 1)
            p[k] += __shfl_xor(p[k], off, 64);
    }
    if ((t & 63) == 0) {
#pragma unroll
        for (int k = 0; k < NNBR; ++k) atomicAdd(&s_sc[k], p[k]);
    }
    __syncthreads();

    float m = s_sc[0];
#pragma unroll
    for (int k = 1; k < NNBR; ++k) m = fmaxf(m, s_sc[k]);
    float e[NNBR], ssum = 0.0f;
#pragma unroll
    for (int k = 0; k < NNBR; ++k) { e[k] = expf(s_sc[k] - m); ssum += e[k]; }
    const float inv = 1.0f / ssum;
    float agg = 0.0f;
#pragma unroll
    for (int k = 0; k < NNBR; ++k) agg = fmaf(e[k], nbr[k], agg);

    hidden_bf[(size_t)b * DIM + t] = f2bf(self_d + agg * inv);
}

// ---------------- K2: row-stripe fused GEMM — block owns 16 rows x ALL 512 cols ----------------
// 64 blocks x 512 thr (8 waves); wave w covers cols w*64 (4 n-frags), all waves same 16 rows.
// out[b] finished IN-BLOCK (LDS reduce over waves); c accumulated via atomicAdd into final buffer.
// No fences, no tickets — only data atomics (measured neutral R3->R6).
__global__ __launch_bounds__(512) void k_item_fused(
    const ushort* __restrict__ hidden, const ushort* __restrict__ Wb,
    const float* __restrict__ b_agg, const int* __restrict__ u,
    const float* __restrict__ usr_emb, const float* __restrict__ W_lin,
    float* __restrict__ out, float* __restrict__ c)
{
    __shared__ float s_wl[NCTX][16];     // W_lin tile [n][row_local]
    __shared__ int s_uid[16];
    __shared__ float s_dp[8][16];        // [wave][row_local] out-dot partials
    const int tid = threadIdx.x;
    const int lane = tid & 63, w = tid >> 6;
    const int m0 = blockIdx.x * 16;
    const int r = lane & 15;             // frag row/col index
    const int kb = lane >> 4;            // k-subblock

    if (tid < 256) {
        const int n = tid >> 4, q = tid & 15;
        s_wl[n][q] = W_lin[n * BATCH + m0 + q];
    } else if (tid < 272) {
        s_uid[tid - 256] = u[m0 + (tid - 256)];
    }
    __syncthreads();

    // ---- GEMM: A = hidden[m0..m0+16][:], B-cols = w*64..w*64+64 ----
    f32x4 acc[4] = {};
    const ushort* Ap = hidden + (size_t)(m0 + r) * DIM + kb * 8;
    const ushort* Bp = Wb + (size_t)(w * 64 + r) * DIM + kb * 8;
#pragma unroll
    for (int k0 = 0; k0 < DIM; k0 += 32) {
        const bf16x8 a = *(const bf16x8*)(Ap + k0);
#pragma unroll
        for (int ni = 0; ni < 4; ++ni) {
            const bf16x8 bb = *(const bf16x8*)(Bp + (size_t)ni * 16 * DIM + k0);
            acc[ni] = __builtin_amdgcn_mfma_f32_16x16x32_bf16(a, bb, acc[ni], 0, 0, 0);
        }
    }

    // ---- epilogue: tanh + bias, out-dot partials, c partials ----
    // C/D layout: col = w*64 + ni*16 + r, row_local = kb*4 + j
    float vals[4][4];                    // [ni][j]
    float dp[4] = {0.0f, 0.0f, 0.0f, 0.0f};
#pragma unroll
    for (int ni = 0; ni < 4; ++ni) {
        const int col = w * 64 + ni * 16 + r;
        const float bias = b_agg[col];
#pragma unroll
        for (int j = 0; j < 4; ++j) {
            const float vv = tanhf(acc[ni][j] + bias);
            vals[ni][j] = vv;
            dp[j] = fmaf(vv, usr_emb[(size_t)s_uid[kb * 4 + j] * DIM + col], dp[j]);
        }
    }

    float cacc[4][NCTX] = {};            // [ni][n]
#pragma unroll
    for (int j = 0; j < 4; ++j) {
        const int rl = kb * 4 + j;
        float wl[NCTX];
#pragma unroll
        for (int n = 0; n < NCTX; ++n) wl[n] = s_wl[n][rl];
#pragma unroll
        for (int ni = 0; ni < 4; ++ni) {
            const float vv = vals[ni][j];
#pragma unroll
            for (int n = 0; n < NCTX; ++n)
                cacc[ni][n] = fmaf(wl[n], vv, cacc[ni][n]);
        }
    }

    // out-dot: reduce over the 16 col-lanes; lane r==0 of each kb group holds row kb*4+j
#pragma unroll
    for (int j = 0; j < 4; ++j) {
        float d2 = dp[j];
        d2 += __shfl_xor(d2, 1, 64);
        d2 += __shfl_xor(d2, 2, 64);
        d2 += __shfl_xor(d2, 4, 64);
        d2 += __shfl_xor(d2, 8, 64);
        if (r == 0) s_dp[w][kb * 4 + j] = d2;
    }

    // c partials: reduce over the 4 kb groups (rows), then one atomic per (n, col)
#pragma unroll
    for (int ni = 0; ni < 4; ++ni)
#pragma unroll
        for (int n = 0; n < NCTX; ++n) {
            float vv = cacc[ni][n];
            vv += __shfl_xor(vv, 16, 64);
            vv += __shfl_xor(vv, 32, 64);
            if (kb == 0) atomicAdd(&c[(size_t)n * DIM + w * 64 + ni * 16 + r], vv);
        }

    __syncthreads();
    if (tid < 16) {
        float x = 0.0f;
#pragma unroll
        for (int ww = 0; ww < 8; ++ww) x += s_dp[ww][tid];
        out[m0 + tid] = 1.0f / (1.0f + expf(-x));
    }
}

extern "C" void kernel_launch(void* const* d_in, const int* in_sizes, int n_in,
                              void* d_out, int out_size, void* d_ws, size_t ws_size,
                              hipStream_t stream) {
    const int*   u       = (const int*)  d_in[0];
    const int*   v       = (const int*)  d_in[1];
    const int*   adj_ent = (const int*)  d_in[2];
    const int*   adj_rel = (const int*)  d_in[3];
    const float* usr_emb = (const float*)d_in[4];
    const float* ent_emb = (const float*)d_in[5];
    const float* rel_emb = (const float*)d_in[6];
    const float* W_agg   = (const float*)d_in[7];
    const float* b_agg   = (const float*)d_in[8];
    const float* W_lin   = (const float*)d_in[9];
    const float* b_lin   = (const float*)d_in[10];

    float* out = (float*)d_out;            // [1024]
    float* c   = out + BATCH;              // [16][512]

    // ws layout: hidden (1MB) | Wb (0.5MB)
    ushort* hidden = (ushort*)d_ws;
    ushort* Wb     = hidden + (size_t)BATCH * DIM;

    k_hidden<<<BATCH, 512, 0, stream>>>(u, v, adj_ent, adj_rel,
                                        usr_emb, ent_emb, rel_emb, W_agg, b_lin,
                                        hidden, Wb, c);
    k_item_fused<<<64, 512, 0, stream>>>(hidden, Wb, b_agg, u, usr_emb, W_lin, out, c);
}

// Round 9
// 29.740 us; speedup vs baseline: 1.5199x; 1.4465x over previous
//
#include <hip/hip_runtime.h>
#include <math.h>

#define DIM 512
#define NNBR 8
#define NCTX 16
#define BATCH 1024

typedef __attribute__((ext_vector_type(8))) short bf16x8;
typedef __attribute__((ext_vector_type(4))) float f32x4;

// RNE float -> bf16 bits
static __device__ __forceinline__ ushort f2bf(float f) {
    uint u = __float_as_uint(f);
    return (ushort)((u + 0x7fffu + ((u >> 16) & 1u)) >> 16);
}

// ---------------- K1: hidden (4 rows/block, float4 16B/lane gathers) + W_agg->bf16 ----------------
// 256 blocks x 512 threads; 128 threads (2 waves) per batch row.
__global__ __launch_bounds__(512) void k_hidden(
    const int* __restrict__ u, const int* __restrict__ v,
    const int* __restrict__ adj_ent, const int* __restrict__ adj_rel,
    const float* __restrict__ usr_emb, const float* __restrict__ ent_emb,
    const float* __restrict__ rel_emb, const float* __restrict__ W_agg,
    ushort* __restrict__ hidden, ushort* __restrict__ Wb)
{
    const int t = threadIdx.x;
    const int blk = blockIdx.x;

    __shared__ int s_ne[4][NNBR], s_nr[4][NNBR];
    __shared__ float s_sc[4][NNBR];
    const int rl = t >> 7;            // row-local 0..3
    const int q = t & 127;            // 128 threads (2 waves) per row
    const int d0 = q * 4;
    const int brow = blk * 4 + rl;
    const int vid = v[brow];
    const int uid = u[brow];
    if (q < NNBR) {
        s_ne[rl][q] = adj_ent[vid * NNBR + q];
        s_nr[rl][q] = adj_rel[vid * NNBR + q];
        s_sc[rl][q] = 0.0f;
    }
    // W_agg -> bf16, 2 rows per block (512 thr x 2 elems)
    {
        const int wrow = blk * 2 + (t >> 8);
        const int wcol = (t & 255) * 2;
        const float2 wv = *(const float2*)&W_agg[(size_t)wrow * DIM + wcol];
        ushort2 o;
        o.x = f2bf(wv.x);
        o.y = f2bf(wv.y);
        *(ushort2*)&Wb[(size_t)wrow * DIM + wcol] = o;
    }
    __syncthreads();

    const float4 user4 = *(const float4*)&usr_emb[(size_t)uid * DIM + d0];
    const float4 self4 = *(const float4*)&ent_emb[(size_t)vid * DIM + d0];
    float4 nbr4[NNBR];
    float p[NNBR];
#pragma unroll
    for (int k = 0; k < NNBR; ++k) {
        nbr4[k] = *(const float4*)&ent_emb[(size_t)s_ne[rl][k] * DIM + d0];
        const float4 r4 = *(const float4*)&rel_emb[(size_t)s_nr[rl][k] * DIM + d0];
        p[k] = user4.x * r4.x + user4.y * r4.y + user4.z * r4.z + user4.w * r4.w;
    }
#pragma unroll
    for (int k = 0; k < NNBR; ++k) {
#pragma unroll
        for (int off = 32; off >= 1; off >>= 1)
            p[k] += __shfl_xor(p[k], off, 64);
    }
    if ((t & 63) == 0) {
#pragma unroll
        for (int k = 0; k < NNBR; ++k) atomicAdd(&s_sc[rl][k], p[k]);
    }
    __syncthreads();

    float m = s_sc[rl][0];
#pragma unroll
    for (int k = 1; k < NNBR; ++k) m = fmaxf(m, s_sc[rl][k]);
    float e[NNBR], ssum = 0.0f;
#pragma unroll
    for (int k = 0; k < NNBR; ++k) { e[k] = expf(s_sc[rl][k] - m); ssum += e[k]; }
    const float inv = 1.0f / ssum;
    float4 agg = {0.0f, 0.0f, 0.0f, 0.0f};
#pragma unroll
    for (int k = 0; k < NNBR; ++k) {
        agg.x = fmaf(e[k], nbr4[k].x, agg.x);
        agg.y = fmaf(e[k], nbr4[k].y, agg.y);
        agg.z = fmaf(e[k], nbr4[k].z, agg.z);
        agg.w = fmaf(e[k], nbr4[k].w, agg.w);
    }
    ushort4 h;
    h.x = f2bf(self4.x + agg.x * inv);
    h.y = f2bf(self4.y + agg.y * inv);
    h.z = f2bf(self4.z + agg.z * inv);
    h.w = f2bf(self4.w + agg.w * inv);
    *(ushort4*)&hidden[(size_t)brow * DIM + d0] = h;
}

// ---------------- K2: fused bf16-MFMA GEMM + tanh + out/c PARTIALS (no atomics) — R6 exact ----------------
// grid (16,8) x 256 thr = 4 waves (2x2 of 32x32), block tile 64x64.
// c_part[bx][n][col512], out_part[by][row]
__global__ __launch_bounds__(256) void k_item_fused(
    const ushort* __restrict__ hidden, const ushort* __restrict__ Wb,
    const float* __restrict__ b_agg, const int* __restrict__ u,
    const float* __restrict__ usr_emb, const float* __restrict__ W_lin,
    float* __restrict__ out_part, float* __restrict__ c_part)
{
    __shared__ float c_blk[2][NCTX][64];
    __shared__ float s_dp[2][64];        // [wc][local row]
    const int tid = threadIdx.x;
    const int lane = tid & 63, w = tid >> 6;
    const int wr = w >> 1, wc = w & 1;
    const int bx = blockIdx.x, by = blockIdx.y;
    const int m0 = bx * 64 + wr * 32;
    const int n0 = by * 64 + wc * 32;
    const int r = lane & 15;             // A-row / B-col within frag
    const int kb = lane >> 4;            // k-block (8 elems each)

    f32x4 acc[2][2] = {};
    const ushort* Ap = hidden + (size_t)(m0 + r) * DIM + kb * 8;
    const ushort* Bp = Wb     + (size_t)(n0 + r) * DIM + kb * 8;

#pragma unroll
    for (int k0 = 0; k0 < DIM; k0 += 32) {
        bf16x8 a0 = *(const bf16x8*)(Ap + k0);
        bf16x8 a1 = *(const bf16x8*)(Ap + 16 * DIM + k0);
        bf16x8 b0 = *(const bf16x8*)(Bp + k0);
        bf16x8 b1 = *(const bf16x8*)(Bp + 16 * DIM + k0);
        acc[0][0] = __builtin_amdgcn_mfma_f32_16x16x32_bf16(a0, b0, acc[0][0], 0, 0, 0);
        acc[0][1] = __builtin_amdgcn_mfma_f32_16x16x32_bf16(a0, b1, acc[0][1], 0, 0, 0);
        acc[1][0] = __builtin_amdgcn_mfma_f32_16x16x32_bf16(a1, b0, acc[1][0], 0, 0, 0);
        acc[1][1] = __builtin_amdgcn_mfma_f32_16x16x32_bf16(a1, b1, acc[1][1], 0, 0, 0);
    }

    // C/D layout: col = lane&15 (+16*ni), row = mi*16 + kb*4 + reg
    float cacc[NCTX][2] = {};
#pragma unroll
    for (int mi = 0; mi < 2; ++mi)
#pragma unroll
        for (int j = 0; j < 4; ++j) {
            const int row = m0 + mi * 16 + kb * 4 + j;
            const int uid = u[row];
            float vals[2];
            float dp = 0.0f;
#pragma unroll
            for (int ni = 0; ni < 2; ++ni) {
                const int col = n0 + ni * 16 + r;
                const float vv = tanhf(acc[mi][ni][j] + b_agg[col]);
                vals[ni] = vv;
                dp = fmaf(vv, usr_emb[(size_t)uid * DIM + col], dp);
            }
#pragma unroll
            for (int n = 0; n < NCTX; ++n) {
                const float wl = W_lin[n * BATCH + row];   // uniform across 16-lane group
                cacc[n][0] = fmaf(wl, vals[0], cacc[n][0]);
                cacc[n][1] = fmaf(wl, vals[1], cacc[n][1]);
            }
            dp += __shfl_xor(dp, 1, 64);
            dp += __shfl_xor(dp, 2, 64);
            dp += __shfl_xor(dp, 4, 64);
            dp += __shfl_xor(dp, 8, 64);
            if (r == 0) s_dp[wc][wr * 32 + mi * 16 + kb * 4 + j] = dp;
        }

#pragma unroll
    for (int n = 0; n < NCTX; ++n)
#pragma unroll
        for (int ni = 0; ni < 2; ++ni) {
            float vv = cacc[n][ni];
            vv += __shfl_xor(vv, 16, 64);
            vv += __shfl_xor(vv, 32, 64);
            if (kb == 0) c_blk[wr][n][wc * 32 + ni * 16 + r] = vv;
        }
    __syncthreads();

    // out partial: row-dp summed over the 2 wc waves -> out_part[by][bx*64 + lr]
    if (tid < 64)
        out_part[(size_t)by * BATCH + bx * 64 + tid] = s_dp[0][tid] + s_dp[1][tid];

    // c partial: float4 store, no atomics: c_part[bx][n][by*64+col]
    {
        const int idx = tid * 4;             // n*64 + col, all 4 in same n
        const int n = idx >> 6, col = idx & 63;
        float4 o;
        o.x = c_blk[0][n][col + 0] + c_blk[1][n][col + 0];
        o.y = c_blk[0][n][col + 1] + c_blk[1][n][col + 1];
        o.z = c_blk[0][n][col + 2] + c_blk[1][n][col + 2];
        o.w = c_blk[0][n][col + 3] + c_blk[1][n][col + 3];
        *(float4*)&c_part[((size_t)bx * NCTX + n) * DIM + by * 64 + col] = o;
    }
}

// ---------------- K3: finisher — plain-load reductions, no atomics ----------------
__global__ __launch_bounds__(256) void k_finish(
    const float* __restrict__ out_part, const float* __restrict__ c_part,
    const float* __restrict__ b_lin, float* __restrict__ out, float* __restrict__ c)
{
    const int i = blockIdx.x * 256 + threadIdx.x;
    if (blockIdx.x < 4) {
        float x = 0.0f;
#pragma unroll
        for (int by = 0; by < 8; ++by) x += out_part[(size_t)by * BATCH + i];
        out[i] = 1.0f / (1.0f + expf(-x));
    } else {
        const int idx = i - 1024;            // 0..8191
        const int n = idx >> 9, col = idx & 511;
        float x = b_lin[n];
#pragma unroll
        for (int bx = 0; bx < 16; ++bx) x += c_part[((size_t)bx * NCTX + n) * DIM + col];
        c[idx] = x;
    }
}

extern "C" void kernel_launch(void* const* d_in, const int* in_sizes, int n_in,
                              void* d_out, int out_size, void* d_ws, size_t ws_size,
                              hipStream_t stream) {
    const int*   u       = (const int*)  d_in[0];
    const int*   v       = (const int*)  d_in[1];
    const int*   adj_ent = (const int*)  d_in[2];
    const int*   adj_rel = (const int*)  d_in[3];
    const float* usr_emb = (const float*)d_in[4];
    const float* ent_emb = (const float*)d_in[5];
    const float* rel_emb = (const float*)d_in[6];
    const float* W_agg   = (const float*)d_in[7];
    const float* b_agg   = (const float*)d_in[8];
    const float* W_lin   = (const float*)d_in[9];
    const float* b_lin   = (const float*)d_in[10];

    float* out = (float*)d_out;            // [1024]
    float* c   = out + BATCH;              // [16][512]

    // ws layout: hidden (1MB) | Wb (0.5MB) | out_part (32KB) | c_part (512KB)
    ushort* hidden   = (ushort*)d_ws;
    ushort* Wb       = hidden + (size_t)BATCH * DIM;
    float*  out_part = (float*)(Wb + (size_t)DIM * DIM);
    float*  c_part   = out_part + 8 * BATCH;

    k_hidden<<<256, 512, 0, stream>>>(u, v, adj_ent, adj_rel,
                                      usr_emb, ent_emb, rel_emb, W_agg,
                                      hidden, Wb);
    k_item_fused<<<dim3(BATCH / 64, DIM / 64), 256, 0, stream>>>(
        hidden, Wb, b_agg, u, usr_emb, W_lin, out_part, c_part);
    k_finish<<<36, 256, 0, stream>>>(out_part, c_part, b_lin, out, c);
}

// Round 10
// 24.757 us; speedup vs baseline: 1.8258x; 1.2013x over previous
//
#include <hip/hip_runtime.h>
#include <math.h>

#define DIM 512
#define NNBR 8
#define NCTX 16
#define BATCH 1024

typedef __attribute__((ext_vector_type(8))) short bf16x8;
typedef __attribute__((ext_vector_type(4))) float f32x4;

// RNE float -> bf16 bits
static __device__ __forceinline__ ushort f2bf(float f) {
    uint u = __float_as_uint(f);
    return (ushort)((u + 0x7fffu + ((u >> 16) & 1u)) >> 16);
}

// ---------------- K1: hidden (4 rows/block, float4 16B/lane gathers) + W_agg->bf16 ----------------
// 256 blocks x 512 threads; 128 threads (2 waves) per batch row.  (proven R9 form + __expf)
__global__ __launch_bounds__(512) void k_hidden(
    const int* __restrict__ u, const int* __restrict__ v,
    const int* __restrict__ adj_ent, const int* __restrict__ adj_rel,
    const float* __restrict__ usr_emb, const float* __restrict__ ent_emb,
    const float* __restrict__ rel_emb, const float* __restrict__ W_agg,
    ushort* __restrict__ hidden, ushort* __restrict__ Wb)
{
    const int t = threadIdx.x;
    const int blk = blockIdx.x;

    __shared__ int s_ne[4][NNBR], s_nr[4][NNBR];
    __shared__ float s_sc[4][NNBR];
    const int rl = t >> 7;            // row-local 0..3
    const int q = t & 127;            // 128 threads (2 waves) per row
    const int d0 = q * 4;
    const int brow = blk * 4 + rl;
    const int vid = v[brow];
    const int uid = u[brow];
    if (q < NNBR) {
        s_ne[rl][q] = adj_ent[vid * NNBR + q];
        s_nr[rl][q] = adj_rel[vid * NNBR + q];
        s_sc[rl][q] = 0.0f;
    }
    // W_agg -> bf16, 2 rows per block (512 thr x 2 elems)
    {
        const int wrow = blk * 2 + (t >> 8);
        const int wcol = (t & 255) * 2;
        const float2 wv = *(const float2*)&W_agg[(size_t)wrow * DIM + wcol];
        ushort2 o;
        o.x = f2bf(wv.x);
        o.y = f2bf(wv.y);
        *(ushort2*)&Wb[(size_t)wrow * DIM + wcol] = o;
    }
    __syncthreads();

    const float4 user4 = *(const float4*)&usr_emb[(size_t)uid * DIM + d0];
    const float4 self4 = *(const float4*)&ent_emb[(size_t)vid * DIM + d0];
    float4 nbr4[NNBR];
    float p[NNBR];
#pragma unroll
    for (int k = 0; k < NNBR; ++k) {
        nbr4[k] = *(const float4*)&ent_emb[(size_t)s_ne[rl][k] * DIM + d0];
        const float4 r4 = *(const float4*)&rel_emb[(size_t)s_nr[rl][k] * DIM + d0];
        p[k] = user4.x * r4.x + user4.y * r4.y + user4.z * r4.z + user4.w * r4.w;
    }
#pragma unroll
    for (int k = 0; k < NNBR; ++k) {
#pragma unroll
        for (int off = 32; off >= 1; off >>= 1)
            p[k] += __shfl_xor(p[k], off, 64);
    }
    if ((t & 63) == 0) {
#pragma unroll
        for (int k = 0; k < NNBR; ++k) atomicAdd(&s_sc[rl][k], p[k]);
    }
    __syncthreads();

    float m = s_sc[rl][0];
#pragma unroll
    for (int k = 1; k < NNBR; ++k) m = fmaxf(m, s_sc[rl][k]);
    float e[NNBR], ssum = 0.0f;
#pragma unroll
    for (int k = 0; k < NNBR; ++k) { e[k] = __expf(s_sc[rl][k] - m); ssum += e[k]; }
    const float inv = 1.0f / ssum;
    float4 agg = {0.0f, 0.0f, 0.0f, 0.0f};
#pragma unroll
    for (int k = 0; k < NNBR; ++k) {
        agg.x = fmaf(e[k], nbr4[k].x, agg.x);
        agg.y = fmaf(e[k], nbr4[k].y, agg.y);
        agg.z = fmaf(e[k], nbr4[k].z, agg.z);
        agg.w = fmaf(e[k], nbr4[k].w, agg.w);
    }
    ushort4 h;
    h.x = f2bf(self4.x + agg.x * inv);
    h.y = f2bf(self4.y + agg.y * inv);
    h.z = f2bf(self4.z + agg.z * inv);
    h.w = f2bf(self4.w + agg.w * inv);
    *(ushort4*)&hidden[(size_t)brow * DIM + d0] = h;
}

// ---------------- K2: fused bf16-MFMA GEMM + tanh + out/c PARTIALS — full-chip regrid ----------------
// grid (32,8) x 256 thr = 4 waves (2x2 of 16x32 wave-tiles), block tile 32x64.
// 256 blocks -> every CU gets one block (was 128 blocks / half the chip).
// c_part[bx][n][col512] (bx 0..31), out_part[by][row] (by 0..7)
__global__ __launch_bounds__(256) void k_item_fused(
    const ushort* __restrict__ hidden, const ushort* __restrict__ Wb,
    const float* __restrict__ b_agg, const int* __restrict__ u,
    const float* __restrict__ usr_emb, const float* __restrict__ W_lin,
    float* __restrict__ out_part, float* __restrict__ c_part)
{
    __shared__ float c_blk[2][NCTX][64];   // [wm][n][col64]
    __shared__ float s_dp[4][16];          // [wave][row16]
    const int tid = threadIdx.x;
    const int lane = tid & 63, w = tid >> 6;
    const int wm = w >> 1, wn = w & 1;
    const int bx = blockIdx.x, by = blockIdx.y;
    const int m0 = bx * 32 + wm * 16;
    const int n0 = by * 64 + wn * 32;
    const int r = lane & 15;             // A-row / B-col within frag
    const int kb = lane >> 4;            // k-block (8 elems each)

    f32x4 acc[2] = {};
    const ushort* Ap = hidden + (size_t)(m0 + r) * DIM + kb * 8;
    const ushort* Bp = Wb     + (size_t)(n0 + r) * DIM + kb * 8;

#pragma unroll
    for (int k0 = 0; k0 < DIM; k0 += 32) {
        bf16x8 a  = *(const bf16x8*)(Ap + k0);
        bf16x8 b0 = *(const bf16x8*)(Bp + k0);
        bf16x8 b1 = *(const bf16x8*)(Bp + 16 * DIM + k0);
        acc[0] = __builtin_amdgcn_mfma_f32_16x16x32_bf16(a, b0, acc[0], 0, 0, 0);
        acc[1] = __builtin_amdgcn_mfma_f32_16x16x32_bf16(a, b1, acc[1], 0, 0, 0);
    }

    // C/D layout: col = n0 + ni*16 + r, row = m0 + kb*4 + j
    float cacc[NCTX][2] = {};
#pragma unroll
    for (int j = 0; j < 4; ++j) {
        const int row = m0 + kb * 4 + j;
        const int uid = u[row];
        float vals[2];
        float dp = 0.0f;
#pragma unroll
        for (int ni = 0; ni < 2; ++ni) {
            const int col = n0 + ni * 16 + r;
            const float vv = tanhf(acc[ni][j] + b_agg[col]);
            vals[ni] = vv;
            dp = fmaf(vv, usr_emb[(size_t)uid * DIM + col], dp);
        }
#pragma unroll
        for (int n = 0; n < NCTX; ++n) {
            const float wl = W_lin[n * BATCH + row];   // uniform across 16-lane group
            cacc[n][0] = fmaf(wl, vals[0], cacc[n][0]);
            cacc[n][1] = fmaf(wl, vals[1], cacc[n][1]);
        }
        dp += __shfl_xor(dp, 1, 64);
        dp += __shfl_xor(dp, 2, 64);
        dp += __shfl_xor(dp, 4, 64);
        dp += __shfl_xor(dp, 8, 64);
        if (r == 0) s_dp[w][kb * 4 + j] = dp;
    }

    // c partials: reduce over the 4 kb row-groups
#pragma unroll
    for (int n = 0; n < NCTX; ++n)
#pragma unroll
        for (int ni = 0; ni < 2; ++ni) {
            float vv = cacc[n][ni];
            vv += __shfl_xor(vv, 16, 64);
            vv += __shfl_xor(vv, 32, 64);
            if (kb == 0) c_blk[wm][n][wn * 32 + ni * 16 + r] = vv;
        }
    __syncthreads();

    // out partial: sum the 2 wn waves per row -> out_part[by][bx*32 + rowlocal]
    if (tid < 32) {
        const int wmq = tid >> 4, rl = tid & 15;
        out_part[(size_t)by * BATCH + bx * 32 + tid] =
            s_dp[wmq * 2 + 0][rl] + s_dp[wmq * 2 + 1][rl];
    }

    // c partial: 16n x 64col = 1024 elems, float4 per thread
    {
        const int idx = tid * 4;             // n*64 + col
        const int n = idx >> 6, col = idx & 63;
        float4 o;
        o.x = c_blk[0][n][col + 0] + c_blk[1][n][col + 0];
        o.y = c_blk[0][n][col + 1] + c_blk[1][n][col + 1];
        o.z = c_blk[0][n][col + 2] + c_blk[1][n][col + 2];
        o.w = c_blk[0][n][col + 3] + c_blk[1][n][col + 3];
        *(float4*)&c_part[((size_t)bx * NCTX + n) * DIM + by * 64 + col] = o;
    }
}

// ---------------- K3: finisher — plain-load reductions, no atomics ----------------
__global__ __launch_bounds__(256) void k_finish(
    const float* __restrict__ out_part, const float* __restrict__ c_part,
    const float* __restrict__ b_lin, float* __restrict__ out, float* __restrict__ c)
{
    const int i = blockIdx.x * 256 + threadIdx.x;
    if (blockIdx.x < 4) {
        float x = 0.0f;
#pragma unroll
        for (int by = 0; by < 8; ++by) x += out_part[(size_t)by * BATCH + i];
        out[i] = 1.0f / (1.0f + __expf(-x));
    } else {
        const int idx = i - 1024;            // 0..8191
        const int n = idx >> 9, col = idx & 511;
        float x = b_lin[n];
#pragma unroll
        for (int bx = 0; bx < 32; ++bx) x += c_part[((size_t)bx * NCTX + n) * DIM + col];
        c[idx] = x;
    }
}

extern "C" void kernel_launch(void* const* d_in, const int* in_sizes, int n_in,
                              void* d_out, int out_size, void* d_ws, size_t ws_size,
                              hipStream_t stream) {
    const int*   u       = (const int*)  d_in[0];
    const int*   v       = (const int*)  d_in[1];
    const int*   adj_ent = (const int*)  d_in[2];
    const int*   adj_rel = (const int*)  d_in[3];
    const float* usr_emb = (const float*)d_in[4];
    const float* ent_emb = (const float*)d_in[5];
    const float* rel_emb = (const float*)d_in[6];
    const float* W_agg   = (const float*)d_in[7];
    const float* b_agg   = (const float*)d_in[8];
    const float* W_lin   = (const float*)d_in[9];
    const float* b_lin   = (const float*)d_in[10];

    float* out = (float*)d_out;            // [1024]
    float* c   = out + BATCH;              // [16][512]

    // ws layout: hidden (1MB) | Wb (0.5MB) | out_part (32KB) | c_part (1MB)
    ushort* hidden   = (ushort*)d_ws;
    ushort* Wb       = hidden + (size_t)BATCH * DIM;
    float*  out_part = (float*)(Wb + (size_t)DIM * DIM);
    float*  c_part   = out_part + 8 * BATCH;

    k_hidden<<<256, 512, 0, stream>>>(u, v, adj_ent, adj_rel,
                                      usr_emb, ent_emb, rel_emb, W_agg,
                                      hidden, Wb);
    k_item_fused<<<dim3(BATCH / 32, DIM / 64), 256, 0, stream>>>(
        hidden, Wb, b_agg, u, usr_emb, W_lin, out_part, c_part);
    k_finish<<<36, 256, 0, stream>>>(out_part, c_part, b_lin, out, c);
}